// Round 8
// baseline (317.158 us; speedup 1.0000x reference)
//
#include <hip/hip_runtime.h>
#include <hip/hip_bf16.h>

#define B_    2
#define N_    4096
#define NV_   32768
#define HID_  128
#define XD_   128
#define YD_   128
#define ZD_   16
#define PLANE (XD_*YD_*ZD_)      // 262144
#define LOCS  (B_*PLANE)         // 524288
#define STEP  (100.0f/15.0f)
#define KS    4                  // K-split factor (k-chunk = 1024)
#define VBL   160                // v-blocks per seg (160*128 = 20480 > any count)
#define L2E   1.4426950408889634f

typedef __attribute__((ext_vector_type(8)))  short short8;
typedef __attribute__((ext_vector_type(16))) float f32x16;
typedef __attribute__((ext_vector_type(4)))  float fv4;   // native vector for NT stores

__device__ __forceinline__ float anchor_s(int i) {   // log2e-scaled anchor coord
    return fmaf((float)i, STEP * L2E, -50.0f * L2E);
}
__device__ __forceinline__ float fexp2(float x) {
    float r; asm("v_exp_f32 %0, %1" : "=v"(r) : "v"(x)); return r;
}
__device__ __forceinline__ unsigned short f2bf(float x) {
    unsigned u = __float_as_uint(x);
    return (unsigned short)((u + 0x7fffu + ((u >> 16) & 1u)) >> 16);
}
__device__ __forceinline__ void gload16(const void* g, void* l) {
    __builtin_amdgcn_global_load_lds(
        (const __attribute__((address_space(1))) unsigned int*)g,
        (__attribute__((address_space(3))) unsigned int*)l, 16, 0, 0);
}

// ---------------- MLP: 8 rows/block, 4-way ILP on W2 loop ----------------
__global__ __launch_bounds__(256) void mlp_kernel(
    const float* __restrict__ pos, const float* __restrict__ scl,
    const float* __restrict__ rot, const float* __restrict__ opa,
    const float* __restrict__ W1,  const float* __restrict__ b1,
    const float* __restrict__ W2,  const float* __restrict__ b2,
    unsigned short* __restrict__ xwT)
{
    int tid = threadIdx.x;
    int j  = tid & 127;
    int rg = tid >> 7;               // 0..1 -> rows rg*4..rg*4+3
    int r0 = blockIdx.x * 8;
    __shared__ float sin_[8][11];
    __shared__ float h[8][HID_];
    if (tid < 88) {
        int rr = tid / 11, c = tid - rr*11;
        int r = r0 + rr;
        float val;
        if (c < 3)       val = pos[r*3 + c];
        else if (c < 6)  val = scl[r*3 + (c-3)];
        else if (c < 10) val = rot[r*4 + (c-6)];
        else             val = opa[r];
        sin_[rr][c] = val;
    }
    __syncthreads();
    float bb1 = b1[j];
    #pragma unroll
    for (int q = 0; q < 4; ++q) {
        int rr = rg*4 + q;
        float a = bb1;
        #pragma unroll
        for (int i = 0; i < 11; ++i) a = fmaf(sin_[rr][i], W1[i*HID_ + j], a);
        h[rr][j] = fmaxf(a, 0.0f);
    }
    __syncthreads();
    float bb2 = b2[j];
    float o0 = bb2, o1 = bb2, o2 = bb2, o3 = bb2;
    #pragma unroll 4
    for (int k = 0; k < HID_; ++k) {
        float w2 = W2[k*HID_ + j];
        int rb = rg*4;
        o0 = fmaf(h[rb+0][k], w2, o0);
        o1 = fmaf(h[rb+1][k], w2, o1);
        o2 = fmaf(h[rb+2][k], w2, o2);
        o3 = fmaf(h[rb+3][k], w2, o3);
    }
    float o[4] = {o0, o1, o2, o3};
    #pragma unroll
    for (int q = 0; q < 4; ++q) {
        int r = r0 + rg*4 + q;
        int b = r >> 12, n = r & 4095;
        xwT[((size_t)(b*HID_ + j))*N_ + n] = f2bf(o[q]);
    }
}

// ------------- pass A (+ scatter folded in): per-v (m_l2e, 1/l), 8 lanes/v -------------
// pass1: chain-light min d^2 (no sqrt); pass2: pruned sum of 2^(m-d).
__global__ __launch_bounds__(256) void ml_kernel(
    const int* __restrict__ vc, float2* __restrict__ ml,
    int* __restrict__ map, int* __restrict__ cnt, int* __restrict__ vlist)
{
    int gid = blockIdx.x * 256 + threadIdx.x;
    int v = gid >> 3, sub = gid & 7;
    int4 c = ((const int4*)vc)[v];

    // ---- folded scatter: one lane per v ----
    if (sub == 0) {
        int loc = ((c.x*XD_ + c.y)*YD_ + c.z)*ZD_ + c.w;
        atomicMax(&map[loc], v);
        int lane = threadIdx.x & 63;
        unsigned long long act = __ballot(1);             // active (sub==0) lanes
        unsigned long long m1 = __ballot(c.x != 0);
        unsigned long long mymask = c.x ? m1 : (act & ~m1);
        int leader = (int)__ffsll(mymask) - 1;
        int total  = __popcll(mymask);
        int rank   = __popcll(mymask & ((1ull << lane) - 1ull));
        int base = 0;
        if (lane == leader) base = atomicAdd(&cnt[c.x], total);
        base = __shfl(base, leader);
        vlist[c.x*NV_ + base + rank] = v;
    }

    float vx = (float)c.y * L2E, vy = (float)c.z * L2E, vz = (float)c.w * L2E;
    float dz2_[16];
    float mindz2 = 1e30f;
    #pragma unroll 16
    for (int iz = 0; iz < 16; ++iz) {
        float t = vz - anchor_s(iz); dz2_[iz] = t*t;
        mindz2 = fminf(mindz2, dz2_[iz]);
    }
    float dxa = vx - anchor_s(sub*2), dxb = vx - anchor_s(sub*2 + 1);
    float dx2_[2] = {dxa*dxa, dxb*dxb};

    // ---- pass 1: min d^2, 4 accumulators ----
    float md[4] = {1e30f, 1e30f, 1e30f, 1e30f};
    #pragma unroll
    for (int i = 0; i < 2; ++i) {
        for (int iy = 0; iy < 16; ++iy) {
            float dy = vy - anchor_s(iy);
            float bxy = fmaf(dy, dy, dx2_[i]);
            #pragma unroll 16
            for (int iz = 0; iz < 16; ++iz)
                md[iz & 3] = fminf(md[iz & 3], bxy + dz2_[iz]);
        }
    }
    float m2v = fminf(fminf(md[0], md[1]), fminf(md[2], md[3]));
    #pragma unroll
    for (int off = 1; off < 8; off <<= 1) m2v = fminf(m2v, __shfl_xor(m2v, off));
    float m = sqrtf(m2v);

    // ---- pass 2: pruned sum ----
    float lim = m + 34.0f;          // 2^-34 cutoff
    float lim2 = lim * lim;
    float la = 0.f, lb = 0.f;
    #pragma unroll
    for (int i = 0; i < 2; ++i) {
        for (int iy = 0; iy < 16; ++iy) {
            float dy = vy - anchor_s(iy);
            float bxy = fmaf(dy, dy, dx2_[i]);
            if (bxy + mindz2 <= lim2) {
                #pragma unroll 8
                for (int iz = 0; iz < 16; iz += 2) {
                    la += fexp2(m - sqrtf(bxy + dz2_[iz]));
                    lb += fexp2(m - sqrtf(bxy + dz2_[iz+1]));
                }
            }
        }
    }
    float l = la + lb;
    #pragma unroll
    for (int off = 1; off < 8; off <<= 1) l += __shfl_xor(l, off);
    if (sub == 0) ml[v] = make_float2(m, 1.0f / l);
}

// ------------- pass B: partial[ks][v,:] via bf16 MFMA, double-buffered DMA pipeline -------------
// 128v x 128d per block; 4 waves v-split; 32x32x16 MFMA; P computed in A-fragment
// registers; X^T staged via global_load_lds (pre-swizzled source); 1 barrier/tile.
__global__ __launch_bounds__(256) void fuse_kernel(
    const unsigned short* __restrict__ xwT, const float2* __restrict__ ml,
    const int* __restrict__ vc,   const int* __restrict__ vlist,
    const int* __restrict__ cnt,  float* __restrict__ fused_p)
{
    int bid  = blockIdx.x;
    int ks_  = bid & (KS-1);
    int rest = bid >> 2;
    int seg  = (rest >= VBL) ? 1 : 0;
    int bi   = rest - seg*VBL;
    int count = cnt[seg];
    int vbase = bi * 128;
    if (vbase >= count) return;
    int nv = min(128, count - vbase);
    int k0 = ks_ * (N_/KS);

    __shared__ __align__(16) unsigned char sXT[2][16384]; // [buf][128 d][8 blk16] swizzled
    __shared__ int svid[128];

    int tid = threadIdx.x;
    int w  = tid >> 6, l = tid & 63;
    int h  = l >> 5;          // k-half within fragment
    int cl = l & 31;          // A row / C col within wave

    if (tid < 128) svid[tid] = (tid < nv) ? vlist[seg*NV_ + vbase + tid] : -1;

    // per-thread v (A-operand row)
    int vloc = w*32 + cl;
    float pml = -1e30f, pvx = 0.f, pvy = 0.f;
    float dz2_[16];
    #pragma unroll 16
    for (int iz = 0; iz < 16; ++iz) dz2_[iz] = 0.f;
    if (vloc < nv) {
        int vid = vlist[seg*NV_ + vbase + vloc];
        int4 c = ((const int4*)vc)[vid];
        pvx = (float)c.y * L2E; pvy = (float)c.z * L2E;
        float pvz = (float)c.w * L2E;
        pml = ml[vid].x;
        #pragma unroll 16
        for (int iz = 0; iz < 16; ++iz) { float t = pvz - anchor_s(iz); dz2_[iz] = t*t; }
    }

    // staging source: instr i covers d = w*32 + i*8 + (l>>3), k-blk = (l&7)^(d&7)
    int d0s  = w*32 + (l >> 3);
    int blkX = (l & 7) ^ ((l >> 3) & 7);
    const unsigned short* sb = xwT + (size_t)(seg*128 + d0s)*N_ + blkX*8 + k0;

    auto stage = [&](int bsel, int t) {
        char* ldsb = (char*)&sXT[bsel][0] + w*4096;   // wave-uniform; HW adds lane*16
        #pragma unroll
        for (int i = 0; i < 4; ++i)
            gload16(sb + (size_t)i*8*N_ + t*64, ldsb + i*1024);
    };

    f32x16 acc[4];
    #pragma unroll
    for (int i = 0; i < 4; ++i) acc[i] = (f32x16)(0.f);

    const int TILES = (N_/KS)/64;    // 16
    stage(0, 0);

    for (int t = 0; t < TILES; ++t) {
        int cur = t & 1;
        // ---- compute P(t) in A-fragment registers (gives DMA time) ----
        unsigned pk_[4][4];
        int nb = k0 + t*64;
        #pragma unroll
        for (int kss = 0; kss < 4; ++kss) {
            int kg = nb + kss*16;
            float ax = anchor_s(kg >> 8);
            float ay = anchor_s((kg >> 4) & 15);
            float dx = pvx - ax, dy = pvy - ay;
            float bxy = fmaf(dx, dx, dy*dy);
            #pragma unroll
            for (int jj = 0; jj < 4; ++jj) {
                float dA = sqrtf(bxy + dz2_[h*8 + 2*jj]);
                float dB = sqrtf(bxy + dz2_[h*8 + 2*jj + 1]);
                float p0 = fexp2(pml - dA);
                float p1 = fexp2(pml - dB);
                asm("v_cvt_pk_bf16_f32 %0, %1, %2" : "=v"(pk_[kss][jj]) : "v"(p0), "v"(p1));
            }
        }
        __syncthreads();              // drains vmcnt(0): buf[cur] ready; buf[cur^1] free
        if (t + 1 < TILES) stage(cur ^ 1, t + 1);   // overlaps with MFMA below
        // ---- MFMA on buf[cur]: 4 kss x 4 d-tiles ----
        #pragma unroll
        for (int kss = 0; kss < 4; ++kss) {
            union { uint4 q; short8 s; } u8;
            u8.q = make_uint4(pk_[kss][0], pk_[kss][1], pk_[kss][2], pk_[kss][3]);
            short8 af = u8.s;
            #pragma unroll
            for (int df = 0; df < 4; ++df) {
                int row = df*32 + cl;
                int blk = (kss*2 + h) ^ (row & 7);
                short8 bf = *(const short8*)&sXT[cur][row*128 + blk*16];
                acc[df] = __builtin_amdgcn_mfma_f32_32x32x16_bf16(af, bf, acc[df], 0, 0, 0);
            }
        }
    }

    // ---- epilogue: nt stores to this kseg's partial buffer (read-once stream) ----
    float* fp = fused_p + (size_t)ks_ * NV_ * HID_;
    #pragma unroll
    for (int df = 0; df < 4; ++df) {
        int dcol = df*32 + cl;
        #pragma unroll
        for (int reg = 0; reg < 16; ++reg) {
            int vrow = w*32 + (reg & 3) + 8*(reg >> 2) + 4*h;
            int sv = svid[vrow];
            if (sv >= 0)
                __builtin_nontemporal_store(acc[df][reg], &fp[(size_t)sv*HID_ + dcol]);
        }
    }
}

// ------------- reduce: fused[v,d] = (sum_ks partial[ks][v,d]) * il[v] -------------
__global__ __launch_bounds__(256) void reduce_kernel(
    const float* __restrict__ fused_p, const float2* __restrict__ ml,
    float* __restrict__ fused)
{
    int idx = blockIdx.x * 256 + threadIdx.x;   // fv4 index over NV*HID/4
    int v = idx >> 5;                            // 32 fv4 per row
    float il = ml[v].y;
    const size_t stride = (size_t)NV_ * HID_ / 4;
    const fv4* p = (const fv4*)fused_p + idx;
    fv4 a = __builtin_nontemporal_load(&p[0]);
    fv4 b = __builtin_nontemporal_load(&p[stride]);
    fv4 c = __builtin_nontemporal_load(&p[2*stride]);
    fv4 d = __builtin_nontemporal_load(&p[3*stride]);
    fv4 o = (a + b + c + d) * il;
    ((fv4*)fused)[idx] = o;                     // cacheable: out_kernel gathers from L2/L3
}

// ------------- output: full-coverage NT write stream (bypass L3 write-allocate) -------------
__global__ __launch_bounds__(256) void out_kernel(
    const int* __restrict__ map, const float* __restrict__ fused,
    float* __restrict__ out)
{
    int q = blockIdx.x * 256 + threadIdx.x;     // quad id, LOCS/4
    int loc0 = q << 2;
    int b   = loc0 >> 18;
    int rem = loc0 & (PLANE - 1);
    int4 vv = ((const int4*)map)[q];
    const fv4* r0 = (const fv4*)(fused + (size_t)(vv.x < 0 ? 0 : vv.x) * HID_);
    const fv4* r1 = (const fv4*)(fused + (size_t)(vv.y < 0 ? 0 : vv.y) * HID_);
    const fv4* r2 = (const fv4*)(fused + (size_t)(vv.z < 0 ? 0 : vv.z) * HID_);
    const fv4* r3 = (const fv4*)(fused + (size_t)(vv.w < 0 ? 0 : vv.w) * HID_);
    size_t obase = ((size_t)b * HID_) * PLANE + rem;
    const fv4 z4 = (fv4)(0.f);
    #pragma unroll 4
    for (int chb = 0; chb < 32; ++chb) {
        fv4 a = (vv.x >= 0) ? r0[chb] : z4;
        fv4 c = (vv.y >= 0) ? r1[chb] : z4;
        fv4 d = (vv.z >= 0) ? r2[chb] : z4;
        fv4 e = (vv.w >= 0) ? r3[chb] : z4;
        fv4 o0 = {a.x, c.x, d.x, e.x};
        fv4 o1 = {a.y, c.y, d.y, e.y};
        fv4 o2 = {a.z, c.z, d.z, e.z};
        fv4 o3 = {a.w, c.w, d.w, e.w};
        __builtin_nontemporal_store(o0, (fv4*)&out[obase + (size_t)(chb*4 + 0) * PLANE]);
        __builtin_nontemporal_store(o1, (fv4*)&out[obase + (size_t)(chb*4 + 1) * PLANE]);
        __builtin_nontemporal_store(o2, (fv4*)&out[obase + (size_t)(chb*4 + 2) * PLANE]);
        __builtin_nontemporal_store(o3, (fv4*)&out[obase + (size_t)(chb*4 + 3) * PLANE]);
    }
}

extern "C" void kernel_launch(void* const* d_in, const int* in_sizes, int n_in,
                              void* d_out, int out_size, void* d_ws, size_t ws_size,
                              hipStream_t stream) {
    const float* pos = (const float*)d_in[0];
    const float* scl = (const float*)d_in[1];
    const float* rot = (const float*)d_in[2];
    const float* opa = (const float*)d_in[3];
    const float* W1  = (const float*)d_in[4];
    const float* b1  = (const float*)d_in[5];
    const float* W2  = (const float*)d_in[6];
    const float* b2  = (const float*)d_in[7];
    const int*   vc  = (const int*)d_in[8];
    float* out = (float*)d_out;

    char* ws = (char*)d_ws;
    unsigned short* xwT = (unsigned short*)(ws);        // 2 MB: bf16 x^T [b][128][4096]
    float2* ml      = (float2*)(ws + (2u<<20));         // 256 KB
    float*  fused   = (float*) (ws + (4u<<20));         // 16 MB
    float*  fused_p = (float*) (ws + (20u<<20));        // 64 MB: KS partial buffers
    int*    map     = (int*)   (ws + (84u<<20));        // 2 MB
    int*    vlist   = (int*)   (ws + (86u<<20));        // 256 KB
    int*    cnt     = (int*)   (ws + (87u<<20));        // 8 B

    hipMemsetAsync(map, 0xFF, LOCS*sizeof(int), stream);
    hipMemsetAsync(cnt, 0, 2*sizeof(int), stream);

    mlp_kernel<<<(B_*N_)/8, 256, 0, stream>>>(pos, scl, rot, opa, W1, b1, W2, b2, xwT);
    ml_kernel<<<(NV_*8)/256, 256, 0, stream>>>(vc, ml, map, cnt, vlist);
    fuse_kernel<<<2*VBL*KS, 256, 0, stream>>>(xwT, ml, vc, vlist, cnt, fused_p);
    reduce_kernel<<<(NV_*HID_/4)/256, 256, 0, stream>>>(fused_p, ml, fused);
    out_kernel<<<LOCS/(256*4), 256, 0, stream>>>(map, fused, out);
}